// Round 8
// baseline (346.817 us; speedup 1.0000x reference)
//
#include <hip/hip_runtime.h>

#define G_GROUPS 512
#define CNT      8192
#define S_PAIRS  8192
#define BLOCK    1024
#define WAVES    (BLOCK / 64)        // 16
#define PPT      (S_PAIRS / BLOCK)   // 8 pairs per thread

// A 4-record period = 144 B = 9 aligned 16B chunks; CA windows (dwords
// 9k+3..9k+5, k=0..3) live entirely in chunks {0,1,3,5,7,8} — chunks
// 2,4,6 are never loaded. 6 float4 loads cover all 4 windows with
// compile-time extraction (thread owns the whole period).
// Letter-suffixed names: A=chunk0 B=chunk1 C=chunk3 D=chunk5 E=chunk7 F=chunk8.
#define LOADP(c, SRC, P)                                              \
    float4 c##A, c##B, c##C, c##D, c##E, c##F;                        \
    {                                                                 \
        const float* fb = (SRC) + slab + 36 * (size_t)(P);            \
        __builtin_memcpy(&c##A, fb + 0,  16);                         \
        __builtin_memcpy(&c##B, fb + 4,  16);                         \
        __builtin_memcpy(&c##C, fb + 12, 16);                         \
        __builtin_memcpy(&c##D, fb + 20, 16);                         \
        __builtin_memcpy(&c##E, fb + 28, 16);                         \
        __builtin_memcpy(&c##F, fb + 32, 16);                         \
    }

// rec 4P+0: dwords 3,4,5    = A.w B.x B.y
// rec 4P+1: dwords 12,13,14 = C.x C.y C.z
// rec 4P+2: dwords 21,22,23 = D.y D.z D.w
// rec 4P+3: dwords 30,31,32 = E.z E.w F.x
#define WRITEP(c, P)                                                  \
    tab4[4 * (P) + 0] = make_float4(c##A.w, c##B.x, c##B.y, 0.f);     \
    tab4[4 * (P) + 1] = make_float4(c##C.x, c##C.y, c##C.z, 0.f);     \
    tab4[4 * (P) + 2] = make_float4(c##D.y, c##D.z, c##D.w, 0.f);     \
    tab4[4 * (P) + 3] = make_float4(c##E.z, c##E.w, c##F.x, 0.f);

// Barrier without vmcnt drain: publish LDS ops, block barrier, fence.
__device__ __forceinline__ void fencebar() {
    asm volatile("s_waitcnt lgkmcnt(0)" ::: "memory");
    __builtin_amdgcn_s_barrier();
    asm volatile("" ::: "memory");
}

__global__ __launch_bounds__(BLOCK, 4) void rgn_loss_kernel(
    const float* __restrict__ inputs,
    const float* __restrict__ target,
    const int*   __restrict__ left,
    const int*   __restrict__ right,
    float*       __restrict__ out)
{
    __shared__ float4 tab4[CNT];          // 128 KiB, one tensor at a time
    __shared__ float  red[WAVES];

    const int tid   = threadIdx.x;
    const int lane  = tid & 63;
    const int wid   = tid >> 6;
    const int g     = blockIdx.x;
    const int gbase = g * CNT;
    const size_t slab = (size_t)g * (CNT * 9);   // slab base in floats

    const int P0 = tid;                   // this thread's two periods
    const int P1 = tid + BLOCK;

    // ---- Pair indices: coalesced; retire under the input staging ----
    const size_t pbase = (size_t)g * S_PAIRS;
    int li[PPT], ri[PPT];
    #pragma unroll
    for (int i = 0; i < PPT; ++i) {
        li[i] = left [pbase + tid + i * BLOCK] - gbase;   // group-local by construction
        ri[i] = right[pbase + tid + i * BLOCK] - gbase;
    }

    // ---- Stage inputs: 12 chunk loads (6/9 density), extract, publish ----
    LOADP(ia, inputs, P0)
    LOADP(ib, inputs, P1)
    WRITEP(ia, P0)
    WRITEP(ib, P1)
    fencebar();                            // inputs table published

    // ---- Prefetch target chunks; they retire under the d_in gather ----
    LOADP(ta, target, P0)
    LOADP(tb, target, P1)

    // ---- Gather d_in ----
    float din[PPT];
    #pragma unroll
    for (int i = 0; i < PPT; ++i) {
        const float4 L = tab4[li[i]];
        const float4 R = tab4[ri[i]];
        const float dx = L.x - R.x, dy = L.y - R.y, dz = L.z - R.z;
        din[i] = sqrtf(dx * dx + dy * dy + dz * dz);
    }
    fencebar();                            // gather reads done before overwrite

    // ---- Publish target table (extract waits only on target regs) ----
    WRITEP(ta, P0)
    WRITEP(tb, P1)
    fencebar();

    // ---- Gather d_tg, accumulate ----
    float acc = 0.0f;
    #pragma unroll
    for (int i = 0; i < PPT; ++i) {
        const float4 L = tab4[li[i]];
        const float4 R = tab4[ri[i]];
        const float dx = L.x - R.x, dy = L.y - R.y, dz = L.z - R.z;
        const float d  = din[i] - sqrtf(dx * dx + dy * dy + dz * dz);
        acc += d * d;
    }

    // ---- Block reduction -> one atomic ----
    #pragma unroll
    for (int off = 32; off > 0; off >>= 1)
        acc += __shfl_down(acc, off);
    if (lane == 0) red[wid] = acc;
    __syncthreads();
    if (wid == 0) {
        float v = (lane < WAVES) ? red[lane] : 0.0f;
        #pragma unroll
        for (int off = 8; off > 0; off >>= 1)
            v += __shfl_down(v, off);
        if (lane == 0)
            atomicAdd(out, v * (1.0f / ((float)G_GROUPS * (float)S_PAIRS)));
    }
}

extern "C" void kernel_launch(void* const* d_in, const int* in_sizes, int n_in,
                              void* d_out, int out_size, void* d_ws, size_t ws_size,
                              hipStream_t stream) {
    const float* inputs = (const float*)d_in[0];
    const float* target = (const float*)d_in[1];
    const int*   left   = (const int*)d_in[2];
    const int*   right  = (const int*)d_in[3];
    float*       out    = (float*)d_out;

    hipMemsetAsync(out, 0, sizeof(float), stream);   // graph-capture safe
    rgn_loss_kernel<<<G_GROUPS, BLOCK, 0, stream>>>(inputs, target, left, right, out);
}

// Round 9
// 310.229 us; speedup vs baseline: 1.1179x; 1.1179x over previous
//
#include <hip/hip_runtime.h>

#define G_GROUPS 512
#define CNT      8192
#define S_PAIRS  8192
#define BLOCK    1024
#define WAVES    (BLOCK / 64)        // 16
#define PPT      (S_PAIRS / BLOCK)   // 8 pairs per thread

// Non-temporal 16B load (4B-aligned OK — same addresses every passing round
// used via memcpy). volatile asm: issue order pinned, cannot be sunk past the
// gather, 8 results held in distinct VGPRs -> true 8-deep in-flight window.
// 'nt' bypasses L1 allocation — the experiment: is the ~100-entry per-CU
// outstanding-fill cap L1-side?
__device__ __forceinline__ float4 nt_load16(const float* p) {
    float4 v;
    asm volatile("global_load_dwordx4 %0, %1, off nt" : "=v"(v) : "v"(p));
    return v;
}

// Wait for all VMEM returns, then fence the scheduler so no consumer of the
// asm-load results is hoisted above the wait (guide rule #18).
#define VMWAIT0()                                                    \
    do {                                                             \
        asm volatile("s_waitcnt vmcnt(0)" ::: "memory");             \
        __builtin_amdgcn_sched_barrier(0);                           \
    } while (0)

// 8 NT loads of CA rows (16 B at record byte 36r+12), named scalars.
#define LOAD8NT(p, SRC, GB)                                          \
    float4 p##0 = nt_load16((SRC) + (size_t)((GB) + tid + 0 * BLOCK) * 9 + 3); \
    float4 p##1 = nt_load16((SRC) + (size_t)((GB) + tid + 1 * BLOCK) * 9 + 3); \
    float4 p##2 = nt_load16((SRC) + (size_t)((GB) + tid + 2 * BLOCK) * 9 + 3); \
    float4 p##3 = nt_load16((SRC) + (size_t)((GB) + tid + 3 * BLOCK) * 9 + 3); \
    float4 p##4 = nt_load16((SRC) + (size_t)((GB) + tid + 4 * BLOCK) * 9 + 3); \
    float4 p##5 = nt_load16((SRC) + (size_t)((GB) + tid + 5 * BLOCK) * 9 + 3); \
    float4 p##6 = nt_load16((SRC) + (size_t)((GB) + tid + 6 * BLOCK) * 9 + 3); \
    float4 p##7 = nt_load16((SRC) + (size_t)((GB) + tid + 7 * BLOCK) * 9 + 3);

#define WRITE8(p)                                                     \
    tab4[tid + 0 * BLOCK] = p##0;  tab4[tid + 1 * BLOCK] = p##1;      \
    tab4[tid + 2 * BLOCK] = p##2;  tab4[tid + 3 * BLOCK] = p##3;      \
    tab4[tid + 4 * BLOCK] = p##4;  tab4[tid + 5 * BLOCK] = p##5;      \
    tab4[tid + 6 * BLOCK] = p##6;  tab4[tid + 7 * BLOCK] = p##7;

// Barrier without vmcnt drain.
__device__ __forceinline__ void fencebar() {
    asm volatile("s_waitcnt lgkmcnt(0)" ::: "memory");
    __builtin_amdgcn_s_barrier();
    asm volatile("" ::: "memory");
}

__global__ __launch_bounds__(BLOCK, 4) void rgn_loss_kernel(
    const float* __restrict__ inputs,
    const float* __restrict__ target,
    const int*   __restrict__ left,
    const int*   __restrict__ right,
    float*       __restrict__ out)
{
    __shared__ float4 tab4[CNT];          // 128 KiB, one tensor at a time
    __shared__ float  red[WAVES];

    const int tid   = threadIdx.x;
    const int lane  = tid & 63;
    const int wid   = tid >> 6;
    const int g     = blockIdx.x;
    const int gbase = g * CNT;

    // ---- Stage inputs: 8 NT loads issued back-to-back ----
    LOAD8NT(iv, inputs, gbase)

    // ---- Pair indices (plain coalesced loads; retire under the same wait) ----
    const size_t pbase = (size_t)g * S_PAIRS;
    int li[PPT], ri[PPT];
    #pragma unroll
    for (int i = 0; i < PPT; ++i) {
        li[i] = left [pbase + tid + i * BLOCK] - gbase;   // group-local by construction
        ri[i] = right[pbase + tid + i * BLOCK] - gbase;
    }

    VMWAIT0();
    WRITE8(iv)
    fencebar();                            // inputs table published

    // ---- Issue ALL target loads now (pinned by volatile asm — they really
    //      stay in flight under the d_in gather this time) ----
    LOAD8NT(tv, target, gbase)

    // ---- Gather d_in ----
    float din[PPT];
    #pragma unroll
    for (int i = 0; i < PPT; ++i) {
        const float4 L = tab4[li[i]];
        const float4 R = tab4[ri[i]];
        const float dx = L.x - R.x, dy = L.y - R.y, dz = L.z - R.z;
        din[i] = sqrtf(dx * dx + dy * dy + dz * dz);
    }
    fencebar();                            // gather reads done before overwrite

    VMWAIT0();
    WRITE8(tv)
    fencebar();                            // target table published

    // ---- Gather d_tg, accumulate ----
    float acc = 0.0f;
    #pragma unroll
    for (int i = 0; i < PPT; ++i) {
        const float4 L = tab4[li[i]];
        const float4 R = tab4[ri[i]];
        const float dx = L.x - R.x, dy = L.y - R.y, dz = L.z - R.z;
        const float d  = din[i] - sqrtf(dx * dx + dy * dy + dz * dz);
        acc += d * d;
    }

    // ---- Block reduction -> one atomic ----
    #pragma unroll
    for (int off = 32; off > 0; off >>= 1)
        acc += __shfl_down(acc, off);
    if (lane == 0) red[wid] = acc;
    __syncthreads();
    if (wid == 0) {
        float v = (lane < WAVES) ? red[lane] : 0.0f;
        #pragma unroll
        for (int off = 8; off > 0; off >>= 1)
            v += __shfl_down(v, off);
        if (lane == 0)
            atomicAdd(out, v * (1.0f / ((float)G_GROUPS * (float)S_PAIRS)));
    }
}

extern "C" void kernel_launch(void* const* d_in, const int* in_sizes, int n_in,
                              void* d_out, int out_size, void* d_ws, size_t ws_size,
                              hipStream_t stream) {
    const float* inputs = (const float*)d_in[0];
    const float* target = (const float*)d_in[1];
    const int*   left   = (const int*)d_in[2];
    const int*   right  = (const int*)d_in[3];
    float*       out    = (float*)d_out;

    hipMemsetAsync(out, 0, sizeof(float), stream);   // graph-capture safe
    rgn_loss_kernel<<<G_GROUPS, BLOCK, 0, stream>>>(inputs, target, left, right, out);
}